// Round 3
// baseline (153.912 us; speedup 1.0000x reference)
//
#include <hip/hip_runtime.h>

// FeatureShader: pytorch3d softmax_rgb_blend + TexturesVertex barycentric gather.
// N,H,W,K,C = 4,256,256,8,16.
//
// R5: revert R4's superset gather predicate (it 2.4x'd random vfeat line
// traffic -> FETCH 125MB, kernel 44.6us). Back to the EXACT predicate
// w > denom*1e-7 (minimal gather set), and instead shorten the path TO the
// predicate:
// - DPP butterflies: xor1/xor2 via quad_perm (0xB1/0x4E), xor4-after-uniform
//   via row_half_mirror (0x141). VALU-speed (~4cy) instead of ds_swizzle
//   (~40cy). Applied to the max chain AND the denom chain -> thr is ready
//   ~200cy earlier, vfeat gather issues that much sooner.
// - Reduce-scatter reordered d=1,d=2,d=4: first two stages (12 exchanges)
//   are quad_perm DPP; only the last 2 exchanges need ds_swizzle (true xor4
//   of distinct values crosses quads, DPP can't).
// - Kept from R4: unconditional faces fetch right after p2f (faces = 2.4MB,
//   L2-resident; removes one serial memory hop), NT loads for stream-once
//   arrays, NT store for out.

constexpr int KK = 8;
constexpr int CC = 16;

typedef float floatx2 __attribute__((ext_vector_type(2)));

template <int CTRL>
__device__ __forceinline__ float dpp_movf(float x) {
    return __int_as_float(
        __builtin_amdgcn_mov_dpp(__float_as_int(x), CTRL, 0xF, 0xF, true));
}
// quad_perm [1,0,3,2] = xor1
#define DPP_XOR1 0xB1
// quad_perm [2,3,0,1] = xor2
#define DPP_XOR2 0x4E
// row_half_mirror: lane ^ 7 within each 8-lane half-row. After the xor1+xor2
// stages make quads uniform, ^7 == ^4 in value -> completes an 8-lane reduce.
#define DPP_HALF_MIRROR 0x141

__global__ __launch_bounds__(256) void feature_shader(
    const float* __restrict__ dists,
    const float* __restrict__ zbuf,
    const float* __restrict__ bary,
    const float* __restrict__ vfeat,
    const float* __restrict__ bg,
    const int*   __restrict__ p2f,
    const int*   __restrict__ faces,
    float* __restrict__ out,
    int n)   // n = N*H*W*K
{
    const float INV_SIGMA = 1e4f;          // 1/SIGMA
    const float INV_GAMMA = 1e4f;          // 1/GAMMA
    const float EPS       = 1e-10f;
    const float ZFAR      = 100.f;
    const float INV_SPAN  = 1.f / 99.f;    // 1/(ZFAR-ZNEAR)

    int t = blockIdx.x * blockDim.x + threadIdx.x;
    if (t >= n) return;
    int k = t & (KK - 1);

    // Coalesced per-slot loads; stream-once -> nontemporal.
    float z  = __builtin_nontemporal_load(zbuf  + t);
    float dd = __builtin_nontemporal_load(dists + t);
    int   f  = __builtin_nontemporal_load(p2f   + t);

    // Unconditional faces fetch (L2-resident, 2.4MB): issued now so its
    // latency overlaps the whole softmax phase. Clamp so f<0 can't fault.
    int fc = (f >= 0) ? f : 0;
    int v0 = faces[fc * 3 + 0];
    int v1 = faces[fc * 3 + 1];
    int v2 = faces[fc * 3 + 2];

    float zinv = (f >= 0) ? (ZFAR - z) * INV_SPAN : 0.f;

    // Group max over the 8-lane k-group — all DPP (VALU speed).
    float m = zinv;
    m = fmaxf(m, dpp_movf<DPP_XOR1>(m));
    m = fmaxf(m, dpp_movf<DPP_XOR2>(m));
    m = fmaxf(m, dpp_movf<DPP_HALF_MIRROR>(m));   // quads uniform -> ^7 == ^4
    m = fmaxf(m, EPS);

    float delta = fmaxf(__expf((EPS - m) * INV_GAMMA), EPS);
    float prob  = (f >= 0) ? 1.f / (1.f + __expf(dd * INV_SIGMA)) : 0.f;
    float w     = prob * __expf((zinv - m) * INV_GAMMA);

    // Group sum -> denominator — all DPP.
    float denom = w;
    denom += dpp_movf<DPP_XOR1>(denom);
    denom += dpp_movf<DPP_XOR2>(denom);
    denom += dpp_movf<DPP_HALF_MIRROR>(denom);
    denom += delta;
    float thr = denom * 1e-7f;   // EXACT predicate (minimal gather set)

    float acc[CC];
    #pragma unroll
    for (int c = 0; c < CC; ++c) acc[c] = 0.f;

    // Single predicated gather region (avg well under 2 of 8 lanes active).
    if (w > thr) {
        const float* bp = bary + (size_t)t * 3;
        float b0 = __builtin_nontemporal_load(bp + 0) * w;
        float b1 = __builtin_nontemporal_load(bp + 1) * w;
        float b2 = __builtin_nontemporal_load(bp + 2) * w;
        const float4* t0 = (const float4*)(vfeat + (size_t)v0 * CC);
        const float4* t1 = (const float4*)(vfeat + (size_t)v1 * CC);
        const float4* t2 = (const float4*)(vfeat + (size_t)v2 * CC);
        #pragma unroll
        for (int j = 0; j < 4; ++j) {
            float4 a0 = t0[j], a1 = t1[j], a2 = t2[j];
            acc[j * 4 + 0] = b0 * a0.x + b1 * a1.x + b2 * a2.x;
            acc[j * 4 + 1] = b0 * a0.y + b1 * a1.y + b2 * a2.y;
            acc[j * 4 + 2] = b0 * a0.z + b1 * a1.z + b2 * a2.z;
            acc[j * 4 + 3] = b0 * a0.w + b1 * a1.w + b2 * a2.w;
        }
    }

    // Reduce-scatter across the 8-lane group, reordered so the first two
    // stages (12 exchanges) ride DPP quad_perm; only the final stage (2
    // exchanges, true xor4 of distinct values) needs ds_swizzle.
    // Stage keyed on lane bit b keeps channels whose matching bit equals b;
    // final result: lane k holds channels [2k, 2k+1].
    {   // d=1 (channel bit c1 == k0): 16 -> 8, quad_perm xor1
        const int kl[8] = {0, 1, 4, 5, 8, 9, 12, 13};   // c1 == 0
        const int kh[8] = {2, 3, 6, 7, 10, 11, 14, 15}; // c1 == 1
        bool low = (k & 1) == 0;
        float nxt[8];
        #pragma unroll
        for (int i = 0; i < 8; ++i) {
            float send = low ? acc[kh[i]] : acc[kl[i]];
            float recv = dpp_movf<DPP_XOR1>(send);
            nxt[i] = (low ? acc[kl[i]] : acc[kh[i]]) + recv;
        }
        #pragma unroll
        for (int i = 0; i < 8; ++i) acc[i] = nxt[i];
    }
    {   // d=2 (bit c2 == k1): 8 -> 4, quad_perm xor2
        const int kl[4] = {0, 1, 4, 5};
        const int kh[4] = {2, 3, 6, 7};
        bool low = (k & 2) == 0;
        float nxt[4];
        #pragma unroll
        for (int i = 0; i < 4; ++i) {
            float send = low ? acc[kh[i]] : acc[kl[i]];
            float recv = dpp_movf<DPP_XOR2>(send);
            nxt[i] = (low ? acc[kl[i]] : acc[kh[i]]) + recv;
        }
        #pragma unroll
        for (int i = 0; i < 4; ++i) acc[i] = nxt[i];
    }
    {   // d=4 (bit c3 == k2): 4 -> 2, ds_swizzle (crosses quads, distinct vals)
        bool low = (k & 4) == 0;
        float nxt[2];
        #pragma unroll
        for (int i = 0; i < 2; ++i) {
            float send = low ? acc[2 + i] : acc[i];
            float recv = __shfl_xor(send, 4);
            nxt[i] = (low ? acc[i] : acc[2 + i]) + recv;
        }
        acc[0] = nxt[0];
        acc[1] = nxt[1];
    }

    float2 g = ((const float2*)bg)[k];
    float inv_den = 1.f / denom;
    floatx2 o;
    o.x = (acc[0] + delta * g.x) * inv_den;
    o.y = (acc[1] + delta * g.y) * inv_den;
    __builtin_nontemporal_store(o, (floatx2*)out + t);   // coalesced dwordx2
}

extern "C" void kernel_launch(void* const* d_in, const int* in_sizes, int n_in,
                              void* d_out, int out_size, void* d_ws, size_t ws_size,
                              hipStream_t stream) {
    const float* dists = (const float*)d_in[0];
    const float* zbuf  = (const float*)d_in[1];
    const float* bary  = (const float*)d_in[2];
    const float* vfeat = (const float*)d_in[3];
    const float* bg    = (const float*)d_in[4];
    const int*   p2f   = (const int*)d_in[5];
    const int*   faces = (const int*)d_in[6];
    float* out = (float*)d_out;

    int n = in_sizes[0];                   // N*H*W*K = 2097152
    int block = 256;
    int grid = (n + block - 1) / block;    // 8192 blocks

    hipLaunchKernelGGL(feature_shader, dim3(grid), dim3(block), 0, stream,
                       dists, zbuf, bary, vfeat, bg, p2f, faces, out, n);
}

// Round 4
// 129.698 us; speedup vs baseline: 1.1867x; 1.1867x over previous
//
#include <hip/hip_runtime.h>

// FeatureShader: pytorch3d softmax_rgb_blend + TexturesVertex barycentric gather.
// N,H,W,K,C = 4,256,256,8,16.
//
// R6: R5's plan executed WITHOUT arrays. R5's regression was NOT the DPP:
// the select-indexed acc[] defeated SROA and AMDGPUPromoteAlloca moved the
// accumulator to LDS (LDS_Block_Size=16384 = 256thr x 64B, 2.3e7 bank
// conflicts, VGPR 40->32). Everything here is named scalars -> guaranteed
// register-resident.
// Kept (all verified-correct in R5): exact predicate w > denom*1e-7,
// unconditional faces fetch, NT stream loads/store, DPP butterflies for
// max/denom (quad_perm xor1/xor2 + row_half_mirror), DPP-first
// reduce-scatter (12 of 14 exchanges at VALU speed, only the 2 xor4
// exchanges via ds_swizzle).

constexpr int KK = 8;
constexpr int CC = 16;

typedef float floatx2 __attribute__((ext_vector_type(2)));

template <int CTRL>
__device__ __forceinline__ float dpp_movf(float x) {
    return __int_as_float(
        __builtin_amdgcn_mov_dpp(__float_as_int(x), CTRL, 0xF, 0xF, true));
}
#define DPP_XOR1 0xB1          // quad_perm [1,0,3,2]
#define DPP_XOR2 0x4E          // quad_perm [2,3,0,1]
#define DPP_HALF_MIRROR 0x141  // lane ^ 7 within 8-lane half-row

__global__ __launch_bounds__(256) void feature_shader(
    const float* __restrict__ dists,
    const float* __restrict__ zbuf,
    const float* __restrict__ bary,
    const float* __restrict__ vfeat,
    const float* __restrict__ bg,
    const int*   __restrict__ p2f,
    const int*   __restrict__ faces,
    float* __restrict__ out,
    int n)   // n = N*H*W*K
{
    const float INV_SIGMA = 1e4f;
    const float INV_GAMMA = 1e4f;
    const float EPS       = 1e-10f;
    const float ZFAR      = 100.f;
    const float INV_SPAN  = 1.f / 99.f;

    int t = blockIdx.x * blockDim.x + threadIdx.x;
    if (t >= n) return;
    int k = t & (KK - 1);

    // Coalesced per-slot loads; stream-once -> nontemporal.
    float z  = __builtin_nontemporal_load(zbuf  + t);
    float dd = __builtin_nontemporal_load(dists + t);
    int   f  = __builtin_nontemporal_load(p2f   + t);

    // Unconditional faces fetch (2.4MB, L2-resident): latency overlaps the
    // whole softmax phase. Clamp so f<0 can't fault.
    int fc = (f >= 0) ? f : 0;
    int v0 = faces[fc * 3 + 0];
    int v1 = faces[fc * 3 + 1];
    int v2 = faces[fc * 3 + 2];

    float zinv = (f >= 0) ? (ZFAR - z) * INV_SPAN : 0.f;

    // Group max over the 8-lane k-group — all DPP (VALU speed).
    float m = zinv;
    m = fmaxf(m, dpp_movf<DPP_XOR1>(m));
    m = fmaxf(m, dpp_movf<DPP_XOR2>(m));
    m = fmaxf(m, dpp_movf<DPP_HALF_MIRROR>(m));   // quads uniform -> ^7 == ^4
    m = fmaxf(m, EPS);

    float delta = fmaxf(__expf((EPS - m) * INV_GAMMA), EPS);
    float prob  = (f >= 0) ? 1.f / (1.f + __expf(dd * INV_SIGMA)) : 0.f;
    float w     = prob * __expf((zinv - m) * INV_GAMMA);

    // Group sum -> denominator — all DPP.
    float denom = w;
    denom += dpp_movf<DPP_XOR1>(denom);
    denom += dpp_movf<DPP_XOR2>(denom);
    denom += dpp_movf<DPP_HALF_MIRROR>(denom);
    denom += delta;
    float thr = denom * 1e-7f;   // exact predicate (minimal gather set)

    // Accumulator: 16 NAMED scalars (never an array -> never an alloca).
    float x0 = 0.f, x1 = 0.f, x2 = 0.f, x3 = 0.f;
    float x4 = 0.f, x5 = 0.f, x6 = 0.f, x7 = 0.f;
    float x8 = 0.f, x9 = 0.f, x10 = 0.f, x11 = 0.f;
    float x12 = 0.f, x13 = 0.f, x14 = 0.f, x15 = 0.f;

    if (w > thr) {
        const float* bp = bary + (size_t)t * 3;
        float b0 = __builtin_nontemporal_load(bp + 0) * w;
        float b1 = __builtin_nontemporal_load(bp + 1) * w;
        float b2 = __builtin_nontemporal_load(bp + 2) * w;
        const float4* t0 = (const float4*)(vfeat + (size_t)v0 * CC);
        const float4* t1 = (const float4*)(vfeat + (size_t)v1 * CC);
        const float4* t2 = (const float4*)(vfeat + (size_t)v2 * CC);
        float4 a0, a1, a2;
        a0 = t0[0]; a1 = t1[0]; a2 = t2[0];
        x0 = b0 * a0.x + b1 * a1.x + b2 * a2.x;
        x1 = b0 * a0.y + b1 * a1.y + b2 * a2.y;
        x2 = b0 * a0.z + b1 * a1.z + b2 * a2.z;
        x3 = b0 * a0.w + b1 * a1.w + b2 * a2.w;
        a0 = t0[1]; a1 = t1[1]; a2 = t2[1];
        x4 = b0 * a0.x + b1 * a1.x + b2 * a2.x;
        x5 = b0 * a0.y + b1 * a1.y + b2 * a2.y;
        x6 = b0 * a0.z + b1 * a1.z + b2 * a2.z;
        x7 = b0 * a0.w + b1 * a1.w + b2 * a2.w;
        a0 = t0[2]; a1 = t1[2]; a2 = t2[2];
        x8  = b0 * a0.x + b1 * a1.x + b2 * a2.x;
        x9  = b0 * a0.y + b1 * a1.y + b2 * a2.y;
        x10 = b0 * a0.z + b1 * a1.z + b2 * a2.z;
        x11 = b0 * a0.w + b1 * a1.w + b2 * a2.w;
        a0 = t0[3]; a1 = t1[3]; a2 = t2[3];
        x12 = b0 * a0.x + b1 * a1.x + b2 * a2.x;
        x13 = b0 * a0.y + b1 * a1.y + b2 * a2.y;
        x14 = b0 * a0.z + b1 * a1.z + b2 * a2.z;
        x15 = b0 * a0.w + b1 * a1.w + b2 * a2.w;
    }

    // Reduce-scatter 16 -> 2, DPP-first ordering, all named scalars.
    // Stage 1 (xor1, keep channel-bit c1 == k0): DPP quad_perm.
    bool lo1 = (k & 1) == 0;
    float s, r;
    float e0, e1, e2, e3, e4, e5, e6, e7;
    s = lo1 ? x2  : x0;  r = dpp_movf<DPP_XOR1>(s);  e0 = (lo1 ? x0  : x2 ) + r;
    s = lo1 ? x3  : x1;  r = dpp_movf<DPP_XOR1>(s);  e1 = (lo1 ? x1  : x3 ) + r;
    s = lo1 ? x6  : x4;  r = dpp_movf<DPP_XOR1>(s);  e2 = (lo1 ? x4  : x6 ) + r;
    s = lo1 ? x7  : x5;  r = dpp_movf<DPP_XOR1>(s);  e3 = (lo1 ? x5  : x7 ) + r;
    s = lo1 ? x10 : x8;  r = dpp_movf<DPP_XOR1>(s);  e4 = (lo1 ? x8  : x10) + r;
    s = lo1 ? x11 : x9;  r = dpp_movf<DPP_XOR1>(s);  e5 = (lo1 ? x9  : x11) + r;
    s = lo1 ? x14 : x12; r = dpp_movf<DPP_XOR1>(s);  e6 = (lo1 ? x12 : x14) + r;
    s = lo1 ? x15 : x13; r = dpp_movf<DPP_XOR1>(s);  e7 = (lo1 ? x13 : x15) + r;

    // Stage 2 (xor2, keep c2 == k1): DPP quad_perm.
    bool lo2 = (k & 2) == 0;
    float g0, g1, g2, g3;
    s = lo2 ? e2 : e0;  r = dpp_movf<DPP_XOR2>(s);  g0 = (lo2 ? e0 : e2) + r;
    s = lo2 ? e3 : e1;  r = dpp_movf<DPP_XOR2>(s);  g1 = (lo2 ? e1 : e3) + r;
    s = lo2 ? e6 : e4;  r = dpp_movf<DPP_XOR2>(s);  g2 = (lo2 ? e4 : e6) + r;
    s = lo2 ? e7 : e5;  r = dpp_movf<DPP_XOR2>(s);  g3 = (lo2 ? e5 : e7) + r;

    // Stage 3 (xor4, keep c3 == k2): true cross-quad exchange -> ds_swizzle.
    bool lo4 = (k & 4) == 0;
    float h0, h1;
    s = lo4 ? g2 : g0;  r = __shfl_xor(s, 4);  h0 = (lo4 ? g0 : g2) + r;
    s = lo4 ? g3 : g1;  r = __shfl_xor(s, 4);  h1 = (lo4 ? g1 : g3) + r;
    // lane k now holds channels [2k, 2k+1].

    float2 g = ((const float2*)bg)[k];
    float inv_den = 1.f / denom;
    floatx2 o;
    o.x = (h0 + delta * g.x) * inv_den;
    o.y = (h1 + delta * g.y) * inv_den;
    __builtin_nontemporal_store(o, (floatx2*)out + t);   // coalesced dwordx2
}

extern "C" void kernel_launch(void* const* d_in, const int* in_sizes, int n_in,
                              void* d_out, int out_size, void* d_ws, size_t ws_size,
                              hipStream_t stream) {
    const float* dists = (const float*)d_in[0];
    const float* zbuf  = (const float*)d_in[1];
    const float* bary  = (const float*)d_in[2];
    const float* vfeat = (const float*)d_in[3];
    const float* bg    = (const float*)d_in[4];
    const int*   p2f   = (const int*)d_in[5];
    const int*   faces = (const int*)d_in[6];
    float* out = (float*)d_out;

    int n = in_sizes[0];                   // N*H*W*K = 2097152
    int block = 256;
    int grid = (n + block - 1) / block;    // 8192 blocks

    hipLaunchKernelGGL(feature_shader, dim3(grid), dim3(block), 0, stream,
                       dists, zbuf, bary, vfeat, bg, p2f, faces, out, n);
}

// Round 5
// 119.159 us; speedup vs baseline: 1.2916x; 1.0884x over previous
//
#include <hip/hip_runtime.h>

// FeatureShader: pytorch3d softmax_rgb_blend + TexturesVertex barycentric gather.
// N,H,W,K,C = 4,256,256,8,16.
//
// R7 = R6 with ONE semantic change: faces+bary loads move back inside the
// exact predicate. R6's unconditional faces fetch issued 3x64 divergent
// transactions per wave vs 3x~11 predicated (+43% of total request work,
// ~9-10us at ~1 req/cy/CU TA throughput). The DPP softmax made the chain
// short enough that the hoist's latency-hiding no longer pays for 5.7x the
// transactions. Inside the predicate f>=0 is implied (w>thr>0 => prob>0).
//
// Kept from R6 (all verified): named-scalar accumulator (no alloca -> no LDS
// demotion), DPP max/denom butterflies (quad_perm xor1/xor2 +
// row_half_mirror), DPP-first reduce-scatter (12 of 14 exchanges at VALU
// speed), NT loads on stream-once zbuf/dists/p2f, NT store on out.

constexpr int KK = 8;
constexpr int CC = 16;

typedef float floatx2 __attribute__((ext_vector_type(2)));

template <int CTRL>
__device__ __forceinline__ float dpp_movf(float x) {
    return __int_as_float(
        __builtin_amdgcn_mov_dpp(__float_as_int(x), CTRL, 0xF, 0xF, true));
}
#define DPP_XOR1 0xB1          // quad_perm [1,0,3,2]
#define DPP_XOR2 0x4E          // quad_perm [2,3,0,1]
#define DPP_HALF_MIRROR 0x141  // lane ^ 7 within 8-lane half-row

__global__ __launch_bounds__(256) void feature_shader(
    const float* __restrict__ dists,
    const float* __restrict__ zbuf,
    const float* __restrict__ bary,
    const float* __restrict__ vfeat,
    const float* __restrict__ bg,
    const int*   __restrict__ p2f,
    const int*   __restrict__ faces,
    float* __restrict__ out,
    int n)   // n = N*H*W*K
{
    const float INV_SIGMA = 1e4f;
    const float INV_GAMMA = 1e4f;
    const float EPS       = 1e-10f;
    const float ZFAR      = 100.f;
    const float INV_SPAN  = 1.f / 99.f;

    int t = blockIdx.x * blockDim.x + threadIdx.x;
    if (t >= n) return;
    int k = t & (KK - 1);

    // Coalesced per-slot loads; stream-once -> nontemporal.
    float z  = __builtin_nontemporal_load(zbuf  + t);
    float dd = __builtin_nontemporal_load(dists + t);
    int   f  = __builtin_nontemporal_load(p2f   + t);

    float zinv = (f >= 0) ? (ZFAR - z) * INV_SPAN : 0.f;

    // Group max over the 8-lane k-group — all DPP (VALU speed).
    float m = zinv;
    m = fmaxf(m, dpp_movf<DPP_XOR1>(m));
    m = fmaxf(m, dpp_movf<DPP_XOR2>(m));
    m = fmaxf(m, dpp_movf<DPP_HALF_MIRROR>(m));   // quads uniform -> ^7 == ^4
    m = fmaxf(m, EPS);

    float delta = fmaxf(__expf((EPS - m) * INV_GAMMA), EPS);
    float prob  = (f >= 0) ? 1.f / (1.f + __expf(dd * INV_SIGMA)) : 0.f;
    float w     = prob * __expf((zinv - m) * INV_GAMMA);

    // Group sum -> denominator — all DPP.
    float denom = w;
    denom += dpp_movf<DPP_XOR1>(denom);
    denom += dpp_movf<DPP_XOR2>(denom);
    denom += dpp_movf<DPP_HALF_MIRROR>(denom);
    denom += delta;
    float thr = denom * 1e-7f;   // exact predicate (minimal gather set)

    // Accumulator: 16 NAMED scalars (never an array -> never an alloca).
    float x0 = 0.f, x1 = 0.f, x2 = 0.f, x3 = 0.f;
    float x4 = 0.f, x5 = 0.f, x6 = 0.f, x7 = 0.f;
    float x8 = 0.f, x9 = 0.f, x10 = 0.f, x11 = 0.f;
    float x12 = 0.f, x13 = 0.f, x14 = 0.f, x15 = 0.f;

    // Single predicated gather region: only active lanes (~1.4 of 8) issue
    // the divergent faces/bary/vfeat transactions. f >= 0 implied by w > thr.
    if (w > thr) {
        int v0 = faces[f * 3 + 0];
        int v1 = faces[f * 3 + 1];
        int v2 = faces[f * 3 + 2];
        const float* bp = bary + (size_t)t * 3;
        float b0 = bp[0] * w;
        float b1 = bp[1] * w;
        float b2 = bp[2] * w;
        const float4* t0 = (const float4*)(vfeat + (size_t)v0 * CC);
        const float4* t1 = (const float4*)(vfeat + (size_t)v1 * CC);
        const float4* t2 = (const float4*)(vfeat + (size_t)v2 * CC);
        float4 a0, a1, a2;
        a0 = t0[0]; a1 = t1[0]; a2 = t2[0];
        x0 = b0 * a0.x + b1 * a1.x + b2 * a2.x;
        x1 = b0 * a0.y + b1 * a1.y + b2 * a2.y;
        x2 = b0 * a0.z + b1 * a1.z + b2 * a2.z;
        x3 = b0 * a0.w + b1 * a1.w + b2 * a2.w;
        a0 = t0[1]; a1 = t1[1]; a2 = t2[1];
        x4 = b0 * a0.x + b1 * a1.x + b2 * a2.x;
        x5 = b0 * a0.y + b1 * a1.y + b2 * a2.y;
        x6 = b0 * a0.z + b1 * a1.z + b2 * a2.z;
        x7 = b0 * a0.w + b1 * a1.w + b2 * a2.w;
        a0 = t0[2]; a1 = t1[2]; a2 = t2[2];
        x8  = b0 * a0.x + b1 * a1.x + b2 * a2.x;
        x9  = b0 * a0.y + b1 * a1.y + b2 * a2.y;
        x10 = b0 * a0.z + b1 * a1.z + b2 * a2.z;
        x11 = b0 * a0.w + b1 * a1.w + b2 * a2.w;
        a0 = t0[3]; a1 = t1[3]; a2 = t2[3];
        x12 = b0 * a0.x + b1 * a1.x + b2 * a2.x;
        x13 = b0 * a0.y + b1 * a1.y + b2 * a2.y;
        x14 = b0 * a0.z + b1 * a1.z + b2 * a2.z;
        x15 = b0 * a0.w + b1 * a1.w + b2 * a2.w;
    }

    // Reduce-scatter 16 -> 2, DPP-first ordering, all named scalars.
    // Stage 1 (xor1, keep channel-bit c1 == k0): DPP quad_perm.
    bool lo1 = (k & 1) == 0;
    float s, r;
    float e0, e1, e2, e3, e4, e5, e6, e7;
    s = lo1 ? x2  : x0;  r = dpp_movf<DPP_XOR1>(s);  e0 = (lo1 ? x0  : x2 ) + r;
    s = lo1 ? x3  : x1;  r = dpp_movf<DPP_XOR1>(s);  e1 = (lo1 ? x1  : x3 ) + r;
    s = lo1 ? x6  : x4;  r = dpp_movf<DPP_XOR1>(s);  e2 = (lo1 ? x4  : x6 ) + r;
    s = lo1 ? x7  : x5;  r = dpp_movf<DPP_XOR1>(s);  e3 = (lo1 ? x5  : x7 ) + r;
    s = lo1 ? x10 : x8;  r = dpp_movf<DPP_XOR1>(s);  e4 = (lo1 ? x8  : x10) + r;
    s = lo1 ? x11 : x9;  r = dpp_movf<DPP_XOR1>(s);  e5 = (lo1 ? x9  : x11) + r;
    s = lo1 ? x14 : x12; r = dpp_movf<DPP_XOR1>(s);  e6 = (lo1 ? x12 : x14) + r;
    s = lo1 ? x15 : x13; r = dpp_movf<DPP_XOR1>(s);  e7 = (lo1 ? x13 : x15) + r;

    // Stage 2 (xor2, keep c2 == k1): DPP quad_perm.
    bool lo2 = (k & 2) == 0;
    float g0, g1, g2, g3;
    s = lo2 ? e2 : e0;  r = dpp_movf<DPP_XOR2>(s);  g0 = (lo2 ? e0 : e2) + r;
    s = lo2 ? e3 : e1;  r = dpp_movf<DPP_XOR2>(s);  g1 = (lo2 ? e1 : e3) + r;
    s = lo2 ? e6 : e4;  r = dpp_movf<DPP_XOR2>(s);  g2 = (lo2 ? e4 : e6) + r;
    s = lo2 ? e7 : e5;  r = dpp_movf<DPP_XOR2>(s);  g3 = (lo2 ? e5 : e7) + r;

    // Stage 3 (xor4, keep c3 == k2): true cross-quad exchange -> ds_swizzle.
    bool lo4 = (k & 4) == 0;
    float h0, h1;
    s = lo4 ? g2 : g0;  r = __shfl_xor(s, 4);  h0 = (lo4 ? g0 : g2) + r;
    s = lo4 ? g3 : g1;  r = __shfl_xor(s, 4);  h1 = (lo4 ? g1 : g3) + r;
    // lane k now holds channels [2k, 2k+1].

    float2 g = ((const float2*)bg)[k];
    float inv_den = 1.f / denom;
    floatx2 o;
    o.x = (h0 + delta * g.x) * inv_den;
    o.y = (h1 + delta * g.y) * inv_den;
    __builtin_nontemporal_store(o, (floatx2*)out + t);   // coalesced dwordx2
}

extern "C" void kernel_launch(void* const* d_in, const int* in_sizes, int n_in,
                              void* d_out, int out_size, void* d_ws, size_t ws_size,
                              hipStream_t stream) {
    const float* dists = (const float*)d_in[0];
    const float* zbuf  = (const float*)d_in[1];
    const float* bary  = (const float*)d_in[2];
    const float* vfeat = (const float*)d_in[3];
    const float* bg    = (const float*)d_in[4];
    const int*   p2f   = (const int*)d_in[5];
    const int*   faces = (const int*)d_in[6];
    float* out = (float*)d_out;

    int n = in_sizes[0];                   // N*H*W*K = 2097152
    int block = 256;
    int grid = (n + block - 1) / block;    // 8192 blocks

    hipLaunchKernelGGL(feature_shader, dim3(grid), dim3(block), 0, stream,
                       dists, zbuf, bary, vfeat, bg, p2f, faces, out, n);
}

// Round 6
// 118.791 us; speedup vs baseline: 1.2957x; 1.0031x over previous
//
#include <hip/hip_runtime.h>

// FeatureShader: pytorch3d softmax_rgb_blend + TexturesVertex barycentric gather.
// N,H,W,K,C = 4,256,256,8,16.
//
// R8: 2 slots per thread (slot-pair within a pixel). R7 tied the R2 baseline
// (~31.5us kernel): VALUBusy 23% / HBM 35% / occ 65% = latency-bound with ONE
// dependent chain per wave (~80 inst vs ~1300cy chain, x5 waves = ~30% issue).
// Thread u handles slots {2u, 2u+1}; a pixel's 8 slots sit on 4 consecutive
// lanes (quad == pixel). Wins:
//  - two INDEPENDENT predicated gather chains per thread (ILP x2)
//  - z/d/p2f stream loads become dwordx2 (half the requests, 8B/lane)
//  - ALL cross-lane reductions are quad_perm DPP (xor1,xor2) - no ds_swizzle
//    anywhere; in-thread pair reduce is free VALU
//  - reduce-scatter 16->4 channels (12 DPP exchanges); lane ends with 4
//    channels -> single dwordx4 NT store (was 2x dwordx2)
// Kept: named scalars only (no alloca -> no LDS demotion, R5 lesson), exact
// predicate w > denom*1e-7 (minimal gather traffic, R4 lesson), predicated
// faces/bary/vfeat (R6->R7 lesson: 5.7x fewer divergent requests), NT loads
// on streams, NT store on out.

constexpr int CC = 16;

typedef float floatx2 __attribute__((ext_vector_type(2)));
typedef float floatx4 __attribute__((ext_vector_type(4)));
typedef int   intx2   __attribute__((ext_vector_type(2)));

template <int CTRL>
__device__ __forceinline__ float dpp_movf(float x) {
    return __int_as_float(
        __builtin_amdgcn_mov_dpp(__float_as_int(x), CTRL, 0xF, 0xF, true));
}
#define DPP_XOR1 0xB1          // quad_perm [1,0,3,2]
#define DPP_XOR2 0x4E          // quad_perm [2,3,0,1]

// One slot's gather+FMA, accumulating into x0..x15 (named scalars in scope).
#define GATHER_SLOT(F, TT, W)                                                \
    {                                                                        \
        int v0 = faces[(size_t)(F) * 3 + 0];                                 \
        int v1 = faces[(size_t)(F) * 3 + 1];                                 \
        int v2 = faces[(size_t)(F) * 3 + 2];                                 \
        const float* bp = bary + (size_t)(TT) * 3;                           \
        float b0 = bp[0] * (W), b1 = bp[1] * (W), b2 = bp[2] * (W);          \
        const float4* t0 = (const float4*)(vfeat + (size_t)v0 * CC);         \
        const float4* t1 = (const float4*)(vfeat + (size_t)v1 * CC);         \
        const float4* t2 = (const float4*)(vfeat + (size_t)v2 * CC);         \
        float4 a0, a1, a2;                                                   \
        a0 = t0[0]; a1 = t1[0]; a2 = t2[0];                                  \
        x0  += b0 * a0.x + b1 * a1.x + b2 * a2.x;                            \
        x1  += b0 * a0.y + b1 * a1.y + b2 * a2.y;                            \
        x2  += b0 * a0.z + b1 * a1.z + b2 * a2.z;                            \
        x3  += b0 * a0.w + b1 * a1.w + b2 * a2.w;                            \
        a0 = t0[1]; a1 = t1[1]; a2 = t2[1];                                  \
        x4  += b0 * a0.x + b1 * a1.x + b2 * a2.x;                            \
        x5  += b0 * a0.y + b1 * a1.y + b2 * a2.y;                            \
        x6  += b0 * a0.z + b1 * a1.z + b2 * a2.z;                            \
        x7  += b0 * a0.w + b1 * a1.w + b2 * a2.w;                            \
        a0 = t0[2]; a1 = t1[2]; a2 = t2[2];                                  \
        x8  += b0 * a0.x + b1 * a1.x + b2 * a2.x;                            \
        x9  += b0 * a0.y + b1 * a1.y + b2 * a2.y;                            \
        x10 += b0 * a0.z + b1 * a1.z + b2 * a2.z;                            \
        x11 += b0 * a0.w + b1 * a1.w + b2 * a2.w;                            \
        a0 = t0[3]; a1 = t1[3]; a2 = t2[3];                                  \
        x12 += b0 * a0.x + b1 * a1.x + b2 * a2.x;                            \
        x13 += b0 * a0.y + b1 * a1.y + b2 * a2.y;                            \
        x14 += b0 * a0.z + b1 * a1.z + b2 * a2.z;                            \
        x15 += b0 * a0.w + b1 * a1.w + b2 * a2.w;                            \
    }

__global__ __launch_bounds__(256) void feature_shader(
    const float* __restrict__ dists,
    const float* __restrict__ zbuf,
    const float* __restrict__ bary,
    const float* __restrict__ vfeat,
    const float* __restrict__ bg,
    const int*   __restrict__ p2f,
    const int*   __restrict__ faces,
    float* __restrict__ out,
    int n)   // n = N*H*W*K
{
    const float INV_SIGMA = 1e4f;
    const float INV_GAMMA = 1e4f;
    const float EPS       = 1e-10f;
    const float ZFAR      = 100.f;
    const float INV_SPAN  = 1.f / 99.f;

    int u = blockIdx.x * blockDim.x + threadIdx.x;   // slot-pair index
    if (u >= (n >> 1)) return;
    int t = u << 1;                                  // first slot
    int q = threadIdx.x & 3;                         // position in pixel quad

    // Coalesced dwordx2 stream loads (8B/lane), nontemporal.
    floatx2 z2 = __builtin_nontemporal_load((const floatx2*)zbuf  + u);
    floatx2 d2 = __builtin_nontemporal_load((const floatx2*)dists + u);
    intx2   f2 = __builtin_nontemporal_load((const intx2*)  p2f   + u);
    int fa = f2.x, fb = f2.y;

    float zinv0 = (fa >= 0) ? (ZFAR - z2.x) * INV_SPAN : 0.f;
    float zinv1 = (fb >= 0) ? (ZFAR - z2.y) * INV_SPAN : 0.f;

    // Group max over the pixel's 8 slots: free in-thread pair max, then
    // two quad_perm DPP hops across the 4-lane quad.
    float m = fmaxf(zinv0, zinv1);
    m = fmaxf(m, dpp_movf<DPP_XOR1>(m));
    m = fmaxf(m, dpp_movf<DPP_XOR2>(m));
    m = fmaxf(m, EPS);

    float delta = fmaxf(__expf((EPS - m) * INV_GAMMA), EPS);
    float prob0 = (fa >= 0) ? 1.f / (1.f + __expf(d2.x * INV_SIGMA)) : 0.f;
    float prob1 = (fb >= 0) ? 1.f / (1.f + __expf(d2.y * INV_SIGMA)) : 0.f;
    float w0 = prob0 * __expf((zinv0 - m) * INV_GAMMA);
    float w1 = prob1 * __expf((zinv1 - m) * INV_GAMMA);

    // Group sum -> denominator, same quad-DPP pattern.
    float denom = w0 + w1;
    denom += dpp_movf<DPP_XOR1>(denom);
    denom += dpp_movf<DPP_XOR2>(denom);
    denom += delta;
    float thr = denom * 1e-7f;   // exact predicate (minimal gather set)

    // Accumulator: 16 NAMED scalars (never an array -> never an alloca).
    float x0 = 0.f, x1 = 0.f, x2 = 0.f, x3 = 0.f;
    float x4 = 0.f, x5 = 0.f, x6 = 0.f, x7 = 0.f;
    float x8 = 0.f, x9 = 0.f, x10 = 0.f, x11 = 0.f;
    float x12 = 0.f, x13 = 0.f, x14 = 0.f, x15 = 0.f;

    // Two INDEPENDENT predicated gathers (ILP): w>thr implies f>=0.
    if (w0 > thr) GATHER_SLOT(fa, t,     w0);
    if (w1 > thr) GATHER_SLOT(fb, t + 1, w1);

    // Reduce-scatter 16 -> 4 across the quad, all quad_perm DPP.
    // Stage 1 (xor1): keep channels with c2 == q0.
    //   q0=0 keeps {0,1,2,3,8,9,10,11}; q0=1 keeps those +4.
    bool lo1 = (q & 1) == 0;
    float s, r;
    float e0, e1, e2, e3, e4, e5, e6, e7;
    s = lo1 ? x4  : x0;  r = dpp_movf<DPP_XOR1>(s);  e0 = (lo1 ? x0  : x4 ) + r;
    s = lo1 ? x5  : x1;  r = dpp_movf<DPP_XOR1>(s);  e1 = (lo1 ? x1  : x5 ) + r;
    s = lo1 ? x6  : x2;  r = dpp_movf<DPP_XOR1>(s);  e2 = (lo1 ? x2  : x6 ) + r;
    s = lo1 ? x7  : x3;  r = dpp_movf<DPP_XOR1>(s);  e3 = (lo1 ? x3  : x7 ) + r;
    s = lo1 ? x12 : x8;  r = dpp_movf<DPP_XOR1>(s);  e4 = (lo1 ? x8  : x12) + r;
    s = lo1 ? x13 : x9;  r = dpp_movf<DPP_XOR1>(s);  e5 = (lo1 ? x9  : x13) + r;
    s = lo1 ? x14 : x10; r = dpp_movf<DPP_XOR1>(s);  e6 = (lo1 ? x10 : x14) + r;
    s = lo1 ? x15 : x11; r = dpp_movf<DPP_XOR1>(s);  e7 = (lo1 ? x11 : x15) + r;

    // Stage 2 (xor2): keep channels with c3 == q1 (j<4 vs j>=4).
    bool lo2 = (q & 2) == 0;
    float g0, g1, g2, g3;
    s = lo2 ? e4 : e0;  r = dpp_movf<DPP_XOR2>(s);  g0 = (lo2 ? e0 : e4) + r;
    s = lo2 ? e5 : e1;  r = dpp_movf<DPP_XOR2>(s);  g1 = (lo2 ? e1 : e5) + r;
    s = lo2 ? e6 : e2;  r = dpp_movf<DPP_XOR2>(s);  g2 = (lo2 ? e2 : e6) + r;
    s = lo2 ? e7 : e3;  r = dpp_movf<DPP_XOR2>(s);  g3 = (lo2 ? e3 : e7) + r;
    // Lane q now holds channels [4q .. 4q+3].

    float4 bgv = ((const float4*)bg)[q];
    float inv_den = 1.f / denom;
    floatx4 o;
    o.x = (g0 + delta * bgv.x) * inv_den;
    o.y = (g1 + delta * bgv.y) * inv_den;
    o.z = (g2 + delta * bgv.z) * inv_den;
    o.w = (g3 + delta * bgv.w) * inv_den;
    __builtin_nontemporal_store(o, (floatx4*)out + u);   // dwordx4, coalesced
}

extern "C" void kernel_launch(void* const* d_in, const int* in_sizes, int n_in,
                              void* d_out, int out_size, void* d_ws, size_t ws_size,
                              hipStream_t stream) {
    const float* dists = (const float*)d_in[0];
    const float* zbuf  = (const float*)d_in[1];
    const float* bary  = (const float*)d_in[2];
    const float* vfeat = (const float*)d_in[3];
    const float* bg    = (const float*)d_in[4];
    const int*   p2f   = (const int*)d_in[5];
    const int*   faces = (const int*)d_in[6];
    float* out = (float*)d_out;

    int n = in_sizes[0];                   // N*H*W*K = 2097152
    int pairs = n >> 1;                    // 1048576 threads
    int block = 256;
    int grid = (pairs + block - 1) / block;  // 4096 blocks

    hipLaunchKernelGGL(feature_shader, dim3(grid), dim3(block), 0, stream,
                       dists, zbuf, bary, vfeat, bg, p2f, faces, out, n);
}